// Round 8
// baseline (312.855 us; speedup 1.0000x reference)
//
#include <hip/hip_runtime.h>
#include <math.h>

typedef unsigned long long u64;
typedef unsigned int u32;

// async global->LDS, 16B per lane; LDS layout must be linear in lane order (it is).
#define GLDS16(gp, lp) __builtin_amdgcn_global_load_lds( \
    (const __attribute__((address_space(1))) void*)(gp), \
    (__attribute__((address_space(3))) void*)(lp), 16, 0, 0)

// ---------------- wave helpers ----------------
__device__ __forceinline__ float wsum(float x) {
#pragma unroll
    for (int o = 1; o < 64; o <<= 1) x += __shfl_xor(x, o);
    return x;
}
__device__ __forceinline__ float wmaxr(float x) {
#pragma unroll
    for (int o = 1; o < 64; o <<= 1) x = fmaxf(x, __shfl_xor(x, o));
    return x;
}

// =================== kA: adjacency + per-row edge list + node projection ===================
// grid 512 x 256 : wave per row
__global__ __launch_bounds__(256) void kA(
    const int* __restrict__ em, const float* __restrict__ nf,
    const float* __restrict__ npw, const float* __restrict__ npb,
    u64* __restrict__ adj, u32* __restrict__ elist, u32* __restrict__ rowCnt,
    float* __restrict__ hbuf)
{
    int t = threadIdx.x, wv = t >> 6, lane = t & 63;
    int g = blockIdx.x * 4 + wv;
    const int* emr = em + (size_t)g * 512;
    u32 run = 0;
#pragma unroll
    for (int s = 0; s < 8; ++s) {
        int j = s * 64 + lane;
        int v = emr[j];
        u64 bal = __ballot(v != 0);
        if (v != 0) {
            u32 slot = run + (u32)__popcll(bal & ((1ULL << lane) - 1ULL));
            if (slot < 96u) elist[g * 96 + slot] = (u32)j;
        }
        if (lane == 0) adj[(size_t)g * 8 + s] = bal;
        run += (u32)__popcll(bal);
    }
    if (lane == 0) rowCnt[g] = run < 96u ? run : 96u;
    float acc = npb[lane];
    const float* r = nf + (size_t)g * 18;
#pragma unroll
    for (int c = 0; c < 18; ++c) acc += r[c] * npw[c * 64 + lane];
    hbuf[(size_t)g * 64 + lane] = acc;
}

// =================== kB: BFS (early-exit) + factored edge-MLP + qkv(l=0) ===================
// grid 512 x 256 : wave per row
__global__ __launch_bounds__(256) void kB(
    const u64* __restrict__ adj, const float* __restrict__ ef,
    const u32* __restrict__ elist, const u32* __restrict__ rowCnt,
    const float* __restrict__ hbuf,
    const float* __restrict__ epw, const float* __restrict__ epb,
    const float* __restrict__ eb1w, const float* __restrict__ eb1b,
    const float* __restrict__ eblng, const float* __restrict__ eblnb,
    const float* __restrict__ eb2w, const float* __restrict__ eb2b,
    const float* __restrict__ wq, const float* __restrict__ wk, const float* __restrict__ wvw,
    unsigned char* __restrict__ spd, float* __restrict__ vals,
    float* __restrict__ Qb, float* __restrict__ KT, float* __restrict__ VT)
{
    __shared__ u64 adjL[4096];                   // 32 KB batch adjacency
    __shared__ u64 bfsS[4][24];                  // per-wave vis/fro/nxt
    __shared__ float MS[684];                    // M[3][8][16] | eb2w 192 | lng 48 | lnb 48 | eb2b 12
    __shared__ u32 pool[384];
    __shared__ u32 offs[5];
    __shared__ u32 cA[4];
    __shared__ int votes[4];
    int t = threadIdx.x, wv = t >> 6, lane = t & 63;
    int g = blockIdx.x * 4 + wv;
    int b = g >> 9, srow = g & 511;
    // stage batch adjacency
    {
        const float4* s = (const float4*)(adj + (size_t)b * 4096);
        float4* d = (float4*)adjL;
#pragma unroll
        for (int u = 0; u < 8; ++u) d[t + u * 256] = s[t + u * 256];
    }
    // precompute M = epw ∘ eb1w (folded bias in row 7) + stage small params
    for (int u = t; u < 384; u += 256) {
        int l = u >> 7, r = u & 127, f = r >> 4, c = r & 15;
        const float* W1 = eb1w + l * 1024 + c;
        float s;
        if (f < 7) {
            s = 0.f;
            const float* ew = epw + f * 64;
            for (int k = 0; k < 64; ++k) s += ew[k] * W1[k * 16];
        } else {
            s = eb1b[l * 16 + c];
            for (int k = 0; k < 64; ++k) s += epb[k] * W1[k * 16];
        }
        MS[u] = s;
    }
    if (t < 192) MS[384 + t] = eb2w[t];
    if (t < 48) { MS[576 + t] = eblng[t]; MS[624 + t] = eblnb[t]; }
    if (t < 12) MS[672 + t] = eb2b[t];
    u64* vis = &bfsS[wv][0]; u64* fro = vis + 8; u64* nxt = vis + 16;
    if (lane < 8) {
        u64 iv = (lane == (srow >> 6)) ? (1ULL << (srow & 63)) : 0ULL;
        vis[lane] = iv; fro[lane] = iv; nxt[lane] = 0ULL;
    }
    __syncthreads();
    // ---- BFS: dist bytes in per-lane register, early exit on empty frontier ----
    u64 myDist = 0x0A0A0A0A0A0A0A0AULL;
    if (lane == (srow >> 3)) myDist &= ~(0xFFULL << ((srow & 7) * 8));
    for (int d = 1; d <= 9; ++d) {
        int c = lane >> 3, w = lane & 7;
        u64 f = fro[c];
        u64 acc = 0ULL;
        while (f) {
            int k = (c << 6) + __builtin_ctzll(f);
            f &= f - 1;
            acc |= adjL[k * 8 + w];
        }
        if (acc) atomicOr(&nxt[w], acc);
        __syncthreads();
        u64 nw = 0ULL;
        if (lane < 8) {
            nw = nxt[lane] & ~vis[lane];
            vis[lane] |= nw; fro[lane] = nw; nxt[lane] = 0ULL;
        }
        u64 bal = __ballot(nw != 0ULL);
        if (lane == 0) votes[wv] = (bal != 0ULL) ? 1 : 0;
        __syncthreads();
        u64 fw = fro[lane >> 3];
        u32 bits = (u32)(fw >> ((lane & 7) * 8)) & 0xFFu;
        if (bits) {
            u64 bm = 0ULL;
#pragma unroll
            for (int kk = 0; kk < 8; ++kk) if (bits & (1u << kk)) bm |= 0xFFULL << (8 * kk);
            myDist = (myDist & ~bm) | ((0x0101010101010101ULL * (u64)(u32)d) & bm);
        }
        if (!(votes[0] | votes[1] | votes[2] | votes[3])) break;
    }
    ((u64*)spd)[(size_t)g * 64 + lane] = myDist;
    // ---- qkv layer 0 (own row) ----
    {
        float hv = hbuf[(size_t)g * 64 + lane];
        float aq = 0.f, ak = 0.f, av = 0.f;
        for (int k = 0; k < 64; ++k) {
            float hk = __shfl(hv, k);
            aq += hk * wq[k * 64 + lane];
            ak += hk * wk[k * 64 + lane];
            av += hk * wvw[k * 64 + lane];
        }
        Qb[(size_t)g * 64 + lane] = aq;
        KT[((size_t)(b * 64 + lane)) * 512 + srow] = ak;
        VT[((size_t)(b * 64 + lane)) * 512 + srow] = av;
    }
    // ---- pool the block's edges, then factored MLP (thread per edge) ----
    u32 cnt = rowCnt[g];
    if (lane == 0) cA[wv] = cnt;
    __syncthreads();
    if (t == 0) {
        u32 a = 0;
        for (int i = 0; i < 4; ++i) { offs[i] = a; a += cA[i]; }
        offs[4] = a;
    }
    __syncthreads();
    u32 base = offs[wv];
    if (lane < (int)cnt)
        pool[base + lane] = ((u32)wv << 16) | ((u32)lane << 9) | elist[g * 96 + lane];
    if (lane + 64 < (int)cnt)
        pool[base + lane + 64] = ((u32)wv << 16) | ((u32)(lane + 64) << 9) | elist[g * 96 + lane + 64];
    __syncthreads();
    u32 tot = offs[4];
    for (u32 e = t; e < tot; e += 256) {
        u32 p = pool[e];
        int rl = (int)(p >> 16);
        u32 s = (p >> 9) & 127u;
        u32 j = p & 511u;
        int ge = blockIdx.x * 4 + rl;
        const float* e7 = ef + ((size_t)ge * 512 + j) * 7;
        float ff[7];
#pragma unroll
        for (int f = 0; f < 7; ++f) ff[f] = e7[f];
#pragma unroll 1
        for (int l = 0; l < 3; ++l) {
            float tt[16];
#pragma unroll
            for (int c = 0; c < 16; ++c) tt[c] = MS[(l * 8 + 7) * 16 + c];
#pragma unroll
            for (int f = 0; f < 7; ++f) {
                float fv = ff[f];
#pragma unroll
                for (int c = 0; c < 16; ++c) tt[c] += fv * MS[(l * 8 + f) * 16 + c];
            }
            float m = 0.f;
#pragma unroll
            for (int c = 0; c < 16; ++c) m += tt[c];
            m *= 0.0625f;
            float var = 0.f;
#pragma unroll
            for (int c = 0; c < 16; ++c) { float d = tt[c] - m; var += d * d; }
            var *= 0.0625f;
            float inv = rsqrtf(var + 1e-5f);
#pragma unroll
            for (int c = 0; c < 16; ++c) {
                float x = (tt[c] - m) * inv * MS[576 + l * 16 + c] + MS[624 + l * 16 + c];
                tt[c] = x >= 0.f ? x : 0.2f * x;
            }
#pragma unroll
            for (int hh = 0; hh < 4; ++hh) {
                float a = MS[672 + l * 4 + hh];
#pragma unroll
                for (int c = 0; c < 16; ++c) a += tt[c] * MS[384 + (l * 16 + c) * 4 + hh];
                vals[(u32)(l * 4 + hh) * 196608u + (u32)ge * 96u + s] = a;
            }
        }
    }
}

// =================== kAttn: block = (b,head) x 16-row tile; wave = 4 rows ===================
// grid 512 x 256 : bh = blk>>5, tile = blk&31 ; K/V staged via async global_load_lds
__global__ __launch_bounds__(256, 2) void kAttn(
    const float* __restrict__ Qb, const float* __restrict__ KTin, const float* __restrict__ VTin,
    const unsigned char* __restrict__ spd, const u32* __restrict__ elist,
    const u32* __restrict__ rowCnt, const float* __restrict__ vals,
    const float* __restrict__ s1w, const float* __restrict__ s1b,
    const float* __restrict__ s2w, const float* __restrict__ s2b,
    const int* __restrict__ nm, int l, float* __restrict__ attO)
{
    __shared__ float kt[8192];                   // [16][512] K tile, then V tile
    __shared__ float bv[8192];                   // [16][512] bias tile; PV scratch per wave
    int t = threadIdx.x, wv = t >> 6, lane = t & 63;
    int bh = blockIdx.x >> 5;
    int tile = blockIdx.x & 31;
    int b = bh >> 2, hh = bh & 3;
    int i0 = tile * 16;
    int rbase = i0 + wv * 4;
    // stage K tile async (32 KB) — runs while we build bias below
    {
        const float4* s = (const float4*)(KTin + ((size_t)(b * 64 + hh * 16)) * 512);
        float4* d = (float4*)kt;
#pragma unroll
        for (int u = 0; u < 8; ++u) GLDS16(s + u * 256 + t, d + u * 256 + t);
    }
    // Q tile -> registers (wave-local broadcast)
    float qv = Qb[((size_t)(b * 512 + rbase + (lane >> 4))) * 64 + hh * 16 + (lane & 15)];
    float q[4][16];
#pragma unroll
    for (int r = 0; r < 4; ++r)
#pragma unroll
        for (int d = 0; d < 16; ++d) q[r][d] = __shfl(qv, r * 16 + d);
    // spd-bias table in lane registers (lane L holds tab[L], L<11)
    float tval;
    {
        int li = lane < 11 ? lane : 10;
        float x = (float)li * 0.1f;
        float a = s2b[l * 4 + hh];
#pragma unroll
        for (int c = 0; c < 16; ++c) {
            float v = x * s1w[l * 16 + c] + s1b[l * 16 + c];
            v = v >= 0.f ? v : 0.2f * v;
            a += v * s2w[(l * 16 + c) * 4 + hh];
        }
        tval = a;
    }
    // bias tile from spd bytes (16 rows, all 256 threads)
    {
        const u32* sp = (const u32*)(spd + ((size_t)(b * 512 + i0)) * 512);
#pragma unroll
        for (int p = 0; p < 8; ++p) {
            int i32 = t + p * 256;
            u32 w4 = sp[i32];
            float4 bb;
            bb.x = __shfl(tval, (int)(w4 & 255u));
            bb.y = __shfl(tval, (int)((w4 >> 8) & 255u));
            bb.z = __shfl(tval, (int)((w4 >> 16) & 255u));
            bb.w = __shfl(tval, (int)(w4 >> 24));
            ((float4*)bv)[i32] = bb;
        }
    }
    __syncthreads();                             // waits vmcnt(0): K staged; bias init done
    // sparse edge overlay (wave writes only its own 4 rows -> no extra sync)
    u32 vp = (u32)(l * 4 + hh) * 196608u;
#pragma unroll
    for (int rr = 0; rr < 4; ++rr) {
        int g = b * 512 + rbase + rr;
        u32 cnt = rowCnt[g];
        for (u32 s = lane; s < cnt; s += 64u) {
            u32 j = elist[g * 96 + s] & 511u;
            bv[(wv * 4 + rr) * 512 + j] = vals[vp + (u32)g * 96u + s];
        }
    }
    // QK + bias + mask
    const int* nmb = nm + b * 512;
    float sc[8][4];
    float mx[4] = {-3e38f, -3e38f, -3e38f, -3e38f};
#pragma unroll
    for (int c = 0; c < 8; ++c) {
        int j = c * 64 + lane;
        float ktv[16];
#pragma unroll
        for (int d = 0; d < 16; ++d) ktv[d] = kt[d * 512 + j];
        float madd = (nmb[j] != 0) ? 0.f : -1e9f;
#pragma unroll
        for (int r = 0; r < 4; ++r) {
            float s = 0.f;
#pragma unroll
            for (int d = 0; d < 16; ++d) s += q[r][d] * ktv[d];
            s = s * 0.25f + bv[(wv * 4 + r) * 512 + j] + madd;
            sc[c][r] = s;
            mx[r] = fmaxf(mx[r], s);
        }
    }
#pragma unroll
    for (int r = 0; r < 4; ++r) mx[r] = wmaxr(mx[r]);
    float sm[4] = {0.f, 0.f, 0.f, 0.f};
#pragma unroll
    for (int c = 0; c < 8; ++c)
#pragma unroll
        for (int r = 0; r < 4; ++r) { sc[c][r] = __expf(sc[c][r] - mx[r]); sm[r] += sc[c][r]; }
#pragma unroll
    for (int r = 0; r < 4; ++r) sm[r] = 1.0f / wsum(sm[r]);
#pragma unroll
    for (int c = 0; c < 8; ++c)
#pragma unroll
        for (int r = 0; r < 4; ++r) sc[c][r] *= sm[r];
    __syncthreads();                             // all waves done reading kt (K)
    // stage V tile async over kt
    {
        const float4* s = (const float4*)(VTin + ((size_t)(b * 64 + hh * 16)) * 512);
        float4* d = (float4*)kt;
#pragma unroll
        for (int u = 0; u < 8; ++u) GLDS16(s + u * 256 + t, d + u * 256 + t);
    }
    __syncthreads();                             // waits vmcnt(0): V staged
    // PV: per-lane partials over this lane's 8 j values
    float acc[4][16];
#pragma unroll
    for (int r = 0; r < 4; ++r)
#pragma unroll
        for (int d = 0; d < 16; ++d) acc[r][d] = 0.f;
#pragma unroll
    for (int c = 0; c < 8; ++c) {
        int j = c * 64 + lane;
#pragma unroll
        for (int d = 0; d < 16; ++d) {
            float v = kt[d * 512 + j];
#pragma unroll
            for (int r = 0; r < 4; ++r) acc[r][d] += sc[c][r] * v;
        }
    }
#pragma unroll
    for (int r = 0; r < 4; ++r)
#pragma unroll
        for (int d = 0; d < 16; ++d) {
            acc[r][d] += __shfl_xor(acc[r][d], 16);
            acc[r][d] += __shfl_xor(acc[r][d], 32);
        }
    // wave-private scratch in own bias rows (only this wave read them)
    float* scr = bv + wv * 2048;                 // 16 x stride-65, conflict-free
    if (lane < 16) {
#pragma unroll
        for (int r = 0; r < 4; ++r)
#pragma unroll
            for (int d = 0; d < 16; ++d) scr[lane * 65 + r * 16 + d] = acc[r][d];
    }
    float o = 0.f;
#pragma unroll
    for (int m = 0; m < 16; ++m) o += scr[m * 65 + lane];
    attO[((size_t)(b * 512 + rbase + (lane >> 4))) * 64 + hh * 16 + (lane & 15)] = o;
}

// =================== kLF: oproj + LN1 + FFN + LN2 + qkv(l+1) [+ score halves at l=2] ===================
// grid 512 x 256 : wave per row
__global__ __launch_bounds__(256) void kLF(
    const float* __restrict__ attO,
    const float* __restrict__ wow, const float* __restrict__ wob,
    const float* __restrict__ ln1g, const float* __restrict__ ln1b,
    const float* __restrict__ f1w, const float* __restrict__ f1b,
    const float* __restrict__ f2w, const float* __restrict__ f2b,
    const float* __restrict__ ln2g, const float* __restrict__ ln2b,
    const float* __restrict__ wqn, const float* __restrict__ wkn, const float* __restrict__ wvn,
    const float* __restrict__ sc1w, const float* __restrict__ sc1b,
    float* __restrict__ hbuf, float* __restrict__ QbOut,
    float* __restrict__ KTout, float* __restrict__ VTout,
    float* __restrict__ egoAcc, float* __restrict__ candAcc,
    int l, float* __restrict__ out)
{
    int t = threadIdx.x, wv = t >> 6, lane = t & 63;
    int g = blockIdx.x * 4 + wv;
    int b = g >> 9, srow = g & 511;
    float hv = hbuf[(size_t)g * 64 + lane];
    float att = attO[(size_t)g * 64 + lane];
    // oproj + residual + LN1
    float h1;
    {
        float a = wob[l * 64 + lane];
        const float* Wo = wow + l * 4096;
        for (int k = 0; k < 64; ++k) a += __shfl(att, k) * Wo[k * 64 + lane];
        float xx = a + hv;
        float mn = wsum(xx) * 0.015625f;
        float d = xx - mn;
        float var = wsum(d * d) * 0.015625f;
        h1 = d * rsqrtf(var + 1e-5f) * ln1g[l * 64 + lane] + ln1b[l * 64 + lane];
    }
    // FFN + residual + LN2
    float hn;
    {
        const float* W1 = f1w + l * 16384;
        const float* W2 = f2w + l * 16384;
        float a1[4];
#pragma unroll
        for (int m = 0; m < 4; ++m) a1[m] = f1b[l * 256 + m * 64 + lane];
        for (int k = 0; k < 64; ++k) {
            float hk = __shfl(h1, k);
#pragma unroll
            for (int m = 0; m < 4; ++m) a1[m] += hk * W1[k * 256 + m * 64 + lane];
        }
        float ffv[4];
#pragma unroll
        for (int m = 0; m < 4; ++m) {
            float u = a1[m];
            ffv[m] = 0.5f * u * (1.0f + erff(u * 0.70710678118654752f));
        }
        // 4 independent accumulator chains (was 1 x 256-step chain)
        float a2p0 = 0.f, a2p1 = 0.f, a2p2 = 0.f, a2p3 = 0.f;
        for (int ll = 0; ll < 64; ++ll) {
            a2p0 += __shfl(ffv[0], ll) * W2[(ll) * 64 + lane];
            a2p1 += __shfl(ffv[1], ll) * W2[(64 + ll) * 64 + lane];
            a2p2 += __shfl(ffv[2], ll) * W2[(128 + ll) * 64 + lane];
            a2p3 += __shfl(ffv[3], ll) * W2[(192 + ll) * 64 + lane];
        }
        float a2 = ((a2p0 + a2p1) + a2p2) + a2p3;
        float xx = a2 + f2b[l * 64 + lane] + h1;
        float mn = wsum(xx) * 0.015625f;
        float d = xx - mn;
        float var = wsum(d * d) * 0.015625f;
        hn = d * rsqrtf(var + 1e-5f) * ln2g[l * 64 + lane] + ln2b[l * 64 + lane];
    }
    hbuf[(size_t)g * 64 + lane] = hn;
    if (l == 2) {
        out[2044 + (size_t)g * 64 + lane] = hn;
        // candidate-half of the score MLP (own row)
        float ca = 0.f;
        for (int k = 0; k < 64; ++k) ca += __shfl(hn, k) * sc1w[(64 + k) * 64 + lane];
        candAcc[(size_t)g * 64 + lane] = ca;
        if (srow == 0) {
            float ea = sc1b[lane];
            for (int k = 0; k < 64; ++k) ea += __shfl(hn, k) * sc1w[k * 64 + lane];
            egoAcc[b * 64 + lane] = ea;
        }
    } else {
        float aq = 0.f, ak = 0.f, av = 0.f;
        for (int k = 0; k < 64; ++k) {
            float hk = __shfl(hn, k);
            aq += hk * wqn[k * 64 + lane];
            ak += hk * wkn[k * 64 + lane];
            av += hk * wvn[k * 64 + lane];
        }
        QbOut[(size_t)g * 64 + lane] = aq;
        KTout[((size_t)(b * 64 + lane)) * 512 + srow] = ak;
        VTout[((size_t)(b * 64 + lane)) * 512 + srow] = av;
    }
}

// =================== kP2: finish scores (wave per candidate) + masked softmax ===================
// grid 4 x 1024 : 16 waves x ~32 candidates each; halves precomputed in kLF(l=2)
__global__ __launch_bounds__(1024) void kP2(
    const float* __restrict__ egoAcc, const float* __restrict__ candAcc,
    const float* __restrict__ lng, const float* __restrict__ lnb,
    const float* __restrict__ s2w, const float* __restrict__ s2b,
    const int* __restrict__ nm, float* __restrict__ out)
{
    __shared__ float lgt[512];
    __shared__ float red[512];
    __shared__ int anyf;
    int b = blockIdx.x, t = threadIdx.x;
    int wave = t >> 6, lane = t & 63;
    if (t == 0) anyf = 0;
    float eacc = egoAcc[b * 64 + lane];
    float lngl = lng[lane], lnbl = lnb[lane];
    float s2wl = s2w[lane], s2b0 = s2b[0];
#pragma unroll 1
    for (int jj = wave; jj < 511; jj += 16) {
        int j = jj + 1;
        float acc = eacc + candAcc[((size_t)(b * 512 + j)) * 64 + lane];
        float mn = wsum(acc) * 0.015625f;
        float d = acc - mn;
        float var = wsum(d * d) * 0.015625f;
        float x = d * rsqrtf(var + 1e-5f) * lngl + lnbl;
        x = x >= 0.f ? x : 0.2f * x;
        float p = wsum(x * s2wl);
        if (lane == 0) lgt[jj] = p + s2b0;
    }
    __syncthreads();
    bool cand = (t < 511) ? (nm[b * 512 + 1 + t] != 0) : false;
    if (cand) atomicOr(&anyf, 1);
    __syncthreads();
    if (t == 0 && anyf == 0) cand = true;
    float val = (t < 511) ? (cand ? lgt[t] : -1e9f) : -3e38f;
    if (t < 512) red[t] = val;
    __syncthreads();
    for (int s = 256; s > 0; s >>= 1) {
        if (t < s) red[t] = fmaxf(red[t], red[t + s]);
        __syncthreads();
    }
    float m = red[0];
    __syncthreads();
    float p = (t < 511) ? __expf(val - m) : 0.f;
    if (t < 512) red[t] = p;
    __syncthreads();
    for (int s = 256; s > 0; s >>= 1) {
        if (t < s) red[t] += red[t + s];
        __syncthreads();
    }
    float inv = 1.0f / red[0];
    if (t < 511) out[b * 511 + t] = p * inv;
}

extern "C" void kernel_launch(void* const* d_in, const int* in_sizes, int n_in,
                              void* d_out, int out_size, void* d_ws, size_t ws_size,
                              hipStream_t stream) {
    const float* nf    = (const float*)d_in[0];
    const float* ef    = (const float*)d_in[1];
    const int*   nm    = (const int*)d_in[2];
    const int*   em    = (const int*)d_in[3];
    const float* npw   = (const float*)d_in[4];
    const float* npb   = (const float*)d_in[5];
    const float* epw   = (const float*)d_in[6];
    const float* epb   = (const float*)d_in[7];
    const float* wq    = (const float*)d_in[8];
    const float* wk    = (const float*)d_in[9];
    const float* wv    = (const float*)d_in[10];
    const float* eb1w  = (const float*)d_in[11];
    const float* eb1b  = (const float*)d_in[12];
    const float* eblng = (const float*)d_in[13];
    const float* eblnb = (const float*)d_in[14];
    const float* eb2w  = (const float*)d_in[15];
    const float* eb2b  = (const float*)d_in[16];
    const float* s1wv  = (const float*)d_in[17];
    const float* s1bv  = (const float*)d_in[18];
    const float* s2wv  = (const float*)d_in[19];
    const float* s2bv  = (const float*)d_in[20];
    const float* wow   = (const float*)d_in[21];
    const float* wob   = (const float*)d_in[22];
    const float* ln1g  = (const float*)d_in[23];
    const float* ln1b  = (const float*)d_in[24];
    const float* ln2g  = (const float*)d_in[25];
    const float* ln2b  = (const float*)d_in[26];
    const float* f1w   = (const float*)d_in[27];
    const float* f1b   = (const float*)d_in[28];
    const float* f2w   = (const float*)d_in[29];
    const float* f2b   = (const float*)d_in[30];
    const float* sc1w  = (const float*)d_in[31];
    const float* sc1b  = (const float*)d_in[32];
    const float* sclng = (const float*)d_in[33];
    const float* sclnb = (const float*)d_in[34];
    const float* sc2w  = (const float*)d_in[35];
    const float* sc2b  = (const float*)d_in[36];

    char* W = (char*)d_ws;
    u64*   adj    = (u64*)(W + 0);              //   131,072 B
    unsigned char* spd = (unsigned char*)(W + 131072);   // 1,048,576 B
    u32*   elist  = (u32*)(W + 1179648);        //   786,432 B [2048][96]
    u32*   rowCnt = (u32*)(W + 1966080);        //     8,192 B
    float* vals   = (float*)(W + 1974272);      // 9,437,184 B [12][2048*96]
    float* hbuf   = (float*)(W + 11411456);     //   524,288 B
    float* Qb     = (float*)(W + 11935744);     //   524,288 B
    float* KT0    = (float*)(W + 12460032);     //   524,288 B
    float* VT0    = (float*)(W + 12984320);     //   524,288 B
    float* KT1    = (float*)(W + 13508608);     //   524,288 B
    float* VT1    = (float*)(W + 14032896);     //   524,288 B
    float* egoAcc = (float*)(W + 14557184);     //     1,024 B
    float* attO   = (float*)(W + 14558208);     //   524,288 B
    float* candAcc= (float*)(W + 15082496);     //   524,288 B

    float* out = (float*)d_out;                 // [probs 2044][h 131072]

    kA<<<512, 256, 0, stream>>>(em, nf, npw, npb, adj, elist, rowCnt, hbuf);
    kB<<<512, 256, 0, stream>>>(adj, ef, elist, rowCnt, hbuf, epw, epb,
                                eb1w, eb1b, eblng, eblnb, eb2w, eb2b,
                                wq, wk, wv, spd, vals, Qb, KT0, VT0);

    kAttn<<<512, 256, 0, stream>>>(Qb, KT0, VT0, spd, elist, rowCnt, vals,
                                   s1wv, s1bv, s2wv, s2bv, nm, 0, attO);
    kLF<<<512, 256, 0, stream>>>(attO, wow, wob, ln1g, ln1b, f1w, f1b, f2w, f2b,
                                 ln2g, ln2b, wq + 4096, wk + 4096, wv + 4096,
                                 sc1w, sc1b, hbuf, Qb, KT1, VT1, egoAcc, candAcc, 0, out);

    kAttn<<<512, 256, 0, stream>>>(Qb, KT1, VT1, spd, elist, rowCnt, vals,
                                   s1wv, s1bv, s2wv, s2bv, nm, 1, attO);
    kLF<<<512, 256, 0, stream>>>(attO, wow, wob, ln1g, ln1b, f1w, f1b, f2w, f2b,
                                 ln2g, ln2b, wq + 8192, wk + 8192, wv + 8192,
                                 sc1w, sc1b, hbuf, Qb, KT0, VT0, egoAcc, candAcc, 1, out);

    kAttn<<<512, 256, 0, stream>>>(Qb, KT0, VT0, spd, elist, rowCnt, vals,
                                   s1wv, s1bv, s2wv, s2bv, nm, 2, attO);
    kLF<<<512, 256, 0, stream>>>(attO, wow, wob, ln1g, ln1b, f1w, f1b, f2w, f2b,
                                 ln2g, ln2b, wq, wk, wv,
                                 sc1w, sc1b, hbuf, Qb, KT1, VT1, egoAcc, candAcc, 2, out);

    kP2<<<4, 1024, 0, stream>>>(egoAcc, candAcc, sclng, sclnb, sc2w, sc2b, nm, out);
}

// Round 9
// 284.343 us; speedup vs baseline: 1.1003x; 1.1003x over previous
//
#include <hip/hip_runtime.h>
#include <math.h>

typedef unsigned long long u64;
typedef unsigned int u32;

// ---------------- wave helpers ----------------
__device__ __forceinline__ float wsum(float x) {
#pragma unroll
    for (int o = 1; o < 64; o <<= 1) x += __shfl_xor(x, o);
    return x;
}
__device__ __forceinline__ float wmaxr(float x) {
#pragma unroll
    for (int o = 1; o < 64; o <<= 1) x = fmaxf(x, __shfl_xor(x, o));
    return x;
}

// =================== kA: adjacency + per-row edge list + node projection ===================
// grid 512 x 256 : wave per row
__global__ __launch_bounds__(256) void kA(
    const int* __restrict__ em, const float* __restrict__ nf,
    const float* __restrict__ npw, const float* __restrict__ npb,
    u64* __restrict__ adj, u32* __restrict__ elist, u32* __restrict__ rowCnt,
    float* __restrict__ hbuf)
{
    int t = threadIdx.x, wv = t >> 6, lane = t & 63;
    int g = blockIdx.x * 4 + wv;
    const int* emr = em + (size_t)g * 512;
    u32 run = 0;
#pragma unroll
    for (int s = 0; s < 8; ++s) {
        int j = s * 64 + lane;
        int v = emr[j];
        u64 bal = __ballot(v != 0);
        if (v != 0) {
            u32 slot = run + (u32)__popcll(bal & ((1ULL << lane) - 1ULL));
            if (slot < 96u) elist[g * 96 + slot] = (u32)j;
        }
        if (lane == 0) adj[(size_t)g * 8 + s] = bal;
        run += (u32)__popcll(bal);
    }
    if (lane == 0) rowCnt[g] = run < 96u ? run : 96u;
    float acc = npb[lane];
    const float* r = nf + (size_t)g * 18;
#pragma unroll
    for (int c = 0; c < 18; ++c) acc += r[c] * npw[c * 64 + lane];
    hbuf[(size_t)g * 64 + lane] = acc;
}

// =================== kB: BFS (early-exit) + factored edge-MLP + qkv(l=0) ===================
// grid 512 x 256 : wave per row
__global__ __launch_bounds__(256) void kB(
    const u64* __restrict__ adj, const float* __restrict__ ef,
    const u32* __restrict__ elist, const u32* __restrict__ rowCnt,
    const float* __restrict__ hbuf,
    const float* __restrict__ epw, const float* __restrict__ epb,
    const float* __restrict__ eb1w, const float* __restrict__ eb1b,
    const float* __restrict__ eblng, const float* __restrict__ eblnb,
    const float* __restrict__ eb2w, const float* __restrict__ eb2b,
    const float* __restrict__ wq, const float* __restrict__ wk, const float* __restrict__ wvw,
    unsigned char* __restrict__ spd, float* __restrict__ vals,
    float* __restrict__ Qb, float* __restrict__ KT, float* __restrict__ VT)
{
    __shared__ u64 adjL[4096];                   // 32 KB batch adjacency
    __shared__ u64 bfsS[4][24];                  // per-wave vis/fro/nxt
    __shared__ float MS[684];                    // M[3][8][16] | eb2w 192 | lng 48 | lnb 48 | eb2b 12
    __shared__ u32 pool[384];
    __shared__ u32 offs[5];
    __shared__ u32 cA[4];
    __shared__ int votes[4];
    int t = threadIdx.x, wv = t >> 6, lane = t & 63;
    int g = blockIdx.x * 4 + wv;
    int b = g >> 9, srow = g & 511;
    // stage batch adjacency
    {
        const float4* s = (const float4*)(adj + (size_t)b * 4096);
        float4* d = (float4*)adjL;
#pragma unroll
        for (int u = 0; u < 8; ++u) d[t + u * 256] = s[t + u * 256];
    }
    // precompute M = epw ∘ eb1w (folded bias in row 7) + stage small params
    for (int u = t; u < 384; u += 256) {
        int l = u >> 7, r = u & 127, f = r >> 4, c = r & 15;
        const float* W1 = eb1w + l * 1024 + c;
        float s;
        if (f < 7) {
            s = 0.f;
            const float* ew = epw + f * 64;
            for (int k = 0; k < 64; ++k) s += ew[k] * W1[k * 16];
        } else {
            s = eb1b[l * 16 + c];
            for (int k = 0; k < 64; ++k) s += epb[k] * W1[k * 16];
        }
        MS[u] = s;
    }
    if (t < 192) MS[384 + t] = eb2w[t];
    if (t < 48) { MS[576 + t] = eblng[t]; MS[624 + t] = eblnb[t]; }
    if (t < 12) MS[672 + t] = eb2b[t];
    u64* vis = &bfsS[wv][0]; u64* fro = vis + 8; u64* nxt = vis + 16;
    if (lane < 8) {
        u64 iv = (lane == (srow >> 6)) ? (1ULL << (srow & 63)) : 0ULL;
        vis[lane] = iv; fro[lane] = iv; nxt[lane] = 0ULL;
    }
    __syncthreads();
    // ---- BFS: dist bytes in per-lane register, early exit on empty frontier ----
    u64 myDist = 0x0A0A0A0A0A0A0A0AULL;
    if (lane == (srow >> 3)) myDist &= ~(0xFFULL << ((srow & 7) * 8));
    for (int d = 1; d <= 9; ++d) {
        int c = lane >> 3, w = lane & 7;
        u64 f = fro[c];
        u64 acc = 0ULL;
        while (f) {
            int k = (c << 6) + __builtin_ctzll(f);
            f &= f - 1;
            acc |= adjL[k * 8 + w];
        }
        if (acc) atomicOr(&nxt[w], acc);
        __syncthreads();
        u64 nw = 0ULL;
        if (lane < 8) {
            nw = nxt[lane] & ~vis[lane];
            vis[lane] |= nw; fro[lane] = nw; nxt[lane] = 0ULL;
        }
        u64 bal = __ballot(nw != 0ULL);
        if (lane == 0) votes[wv] = (bal != 0ULL) ? 1 : 0;
        __syncthreads();
        u64 fw = fro[lane >> 3];
        u32 bits = (u32)(fw >> ((lane & 7) * 8)) & 0xFFu;
        if (bits) {
            u64 bm = 0ULL;
#pragma unroll
            for (int kk = 0; kk < 8; ++kk) if (bits & (1u << kk)) bm |= 0xFFULL << (8 * kk);
            myDist = (myDist & ~bm) | ((0x0101010101010101ULL * (u64)(u32)d) & bm);
        }
        if (!(votes[0] | votes[1] | votes[2] | votes[3])) break;
    }
    ((u64*)spd)[(size_t)g * 64 + lane] = myDist;
    // ---- qkv layer 0 (own row) ----
    {
        float hv = hbuf[(size_t)g * 64 + lane];
        float aq = 0.f, ak = 0.f, av = 0.f;
        for (int k = 0; k < 64; ++k) {
            float hk = __shfl(hv, k);
            aq += hk * wq[k * 64 + lane];
            ak += hk * wk[k * 64 + lane];
            av += hk * wvw[k * 64 + lane];
        }
        Qb[(size_t)g * 64 + lane] = aq;
        KT[((size_t)(b * 64 + lane)) * 512 + srow] = ak;
        VT[((size_t)(b * 64 + lane)) * 512 + srow] = av;
    }
    // ---- pool the block's edges, then factored MLP (thread per edge) ----
    u32 cnt = rowCnt[g];
    if (lane == 0) cA[wv] = cnt;
    __syncthreads();
    if (t == 0) {
        u32 a = 0;
        for (int i = 0; i < 4; ++i) { offs[i] = a; a += cA[i]; }
        offs[4] = a;
    }
    __syncthreads();
    u32 base = offs[wv];
    if (lane < (int)cnt)
        pool[base + lane] = ((u32)wv << 16) | ((u32)lane << 9) | elist[g * 96 + lane];
    if (lane + 64 < (int)cnt)
        pool[base + lane + 64] = ((u32)wv << 16) | ((u32)(lane + 64) << 9) | elist[g * 96 + lane + 64];
    __syncthreads();
    u32 tot = offs[4];
    for (u32 e = t; e < tot; e += 256) {
        u32 p = pool[e];
        int rl = (int)(p >> 16);
        u32 s = (p >> 9) & 127u;
        u32 j = p & 511u;
        int ge = blockIdx.x * 4 + rl;
        const float* e7 = ef + ((size_t)ge * 512 + j) * 7;
        float ff[7];
#pragma unroll
        for (int f = 0; f < 7; ++f) ff[f] = e7[f];
#pragma unroll 1
        for (int l = 0; l < 3; ++l) {
            float tt[16];
#pragma unroll
            for (int c = 0; c < 16; ++c) tt[c] = MS[(l * 8 + 7) * 16 + c];
#pragma unroll
            for (int f = 0; f < 7; ++f) {
                float fv = ff[f];
#pragma unroll
                for (int c = 0; c < 16; ++c) tt[c] += fv * MS[(l * 8 + f) * 16 + c];
            }
            float m = 0.f;
#pragma unroll
            for (int c = 0; c < 16; ++c) m += tt[c];
            m *= 0.0625f;
            float var = 0.f;
#pragma unroll
            for (int c = 0; c < 16; ++c) { float d = tt[c] - m; var += d * d; }
            var *= 0.0625f;
            float inv = rsqrtf(var + 1e-5f);
#pragma unroll
            for (int c = 0; c < 16; ++c) {
                float x = (tt[c] - m) * inv * MS[576 + l * 16 + c] + MS[624 + l * 16 + c];
                tt[c] = x >= 0.f ? x : 0.2f * x;
            }
#pragma unroll
            for (int hh = 0; hh < 4; ++hh) {
                float a = MS[672 + l * 4 + hh];
#pragma unroll
                for (int c = 0; c < 16; ++c) a += tt[c] * MS[384 + (l * 16 + c) * 4 + hh];
                vals[(u32)(l * 4 + hh) * 196608u + (u32)ge * 96u + s] = a;
            }
        }
    }
}

// =================== kAttn: block = (b,head) x 16-row tile; wave = 4 rows ===================
// grid 512 x 256 : bh = blk>>5 (tiles of same head consecutive), tile = blk&31
__global__ __launch_bounds__(256, 2) void kAttn(
    const float* __restrict__ Qb, const float* __restrict__ KTin, const float* __restrict__ VTin,
    const unsigned char* __restrict__ spd, const u32* __restrict__ elist,
    const u32* __restrict__ rowCnt, const float* __restrict__ vals,
    const float* __restrict__ s1w, const float* __restrict__ s1b,
    const float* __restrict__ s2w, const float* __restrict__ s2b,
    const int* __restrict__ nm, int l, float* __restrict__ attO)
{
    __shared__ float kt[8192];                   // [16][512] K tile, then V tile
    __shared__ float bv[8192];                   // [16][512] bias tile; PV scratch per wave
    int t = threadIdx.x, wv = t >> 6, lane = t & 63;
    int bh = blockIdx.x >> 5;
    int tile = blockIdx.x & 31;
    int b = bh >> 2, hh = bh & 3;
    int i0 = tile * 16;
    int rbase = i0 + wv * 4;
    // Q tile -> registers (wave-local broadcast)
    float qv = Qb[((size_t)(b * 512 + rbase + (lane >> 4))) * 64 + hh * 16 + (lane & 15)];
    float q[4][16];
#pragma unroll
    for (int r = 0; r < 4; ++r)
#pragma unroll
        for (int d = 0; d < 16; ++d) q[r][d] = __shfl(qv, r * 16 + d);
    // stage K tile (32 KB)
    {
        const float4* s = (const float4*)(KTin + ((size_t)(b * 64 + hh * 16)) * 512);
        float4* d = (float4*)kt;
#pragma unroll
        for (int u = 0; u < 8; ++u) d[t + u * 256] = s[t + u * 256];
    }
    // spd-bias table in lane registers (lane L holds tab[L], L<11)
    float tval;
    {
        int li = lane < 11 ? lane : 10;
        float x = (float)li * 0.1f;
        float a = s2b[l * 4 + hh];
#pragma unroll
        for (int c = 0; c < 16; ++c) {
            float v = x * s1w[l * 16 + c] + s1b[l * 16 + c];
            v = v >= 0.f ? v : 0.2f * v;
            a += v * s2w[(l * 16 + c) * 4 + hh];
        }
        tval = a;
    }
    // bias tile from spd bytes (16 rows, all 256 threads)
    {
        const u32* sp = (const u32*)(spd + ((size_t)(b * 512 + i0)) * 512);
#pragma unroll
        for (int p = 0; p < 8; ++p) {
            int i32 = t + p * 256;
            u32 w4 = sp[i32];
            float4 bb;
            bb.x = __shfl(tval, (int)(w4 & 255u));
            bb.y = __shfl(tval, (int)((w4 >> 8) & 255u));
            bb.z = __shfl(tval, (int)((w4 >> 16) & 255u));
            bb.w = __shfl(tval, (int)(w4 >> 24));
            ((float4*)bv)[i32] = bb;
        }
    }
    __syncthreads();                             // kt staged + bias init complete
    // sparse edge overlay (wave writes only its own 4 rows -> no extra sync)
    u32 vp = (u32)(l * 4 + hh) * 196608u;
#pragma unroll
    for (int rr = 0; rr < 4; ++rr) {
        int g = b * 512 + rbase + rr;
        u32 cnt = rowCnt[g];
        for (u32 s = lane; s < cnt; s += 64u) {
            u32 j = elist[g * 96 + s] & 511u;
            bv[(wv * 4 + rr) * 512 + j] = vals[vp + (u32)g * 96u + s];
        }
    }
    // QK + bias + mask
    const int* nmb = nm + b * 512;
    float sc[8][4];
    float mx[4] = {-3e38f, -3e38f, -3e38f, -3e38f};
#pragma unroll
    for (int c = 0; c < 8; ++c) {
        int j = c * 64 + lane;
        float ktv[16];
#pragma unroll
        for (int d = 0; d < 16; ++d) ktv[d] = kt[d * 512 + j];
        float madd = (nmb[j] != 0) ? 0.f : -1e9f;
#pragma unroll
        for (int r = 0; r < 4; ++r) {
            float s = 0.f;
#pragma unroll
            for (int d = 0; d < 16; ++d) s += q[r][d] * ktv[d];
            s = s * 0.25f + bv[(wv * 4 + r) * 512 + j] + madd;
            sc[c][r] = s;
            mx[r] = fmaxf(mx[r], s);
        }
    }
#pragma unroll
    for (int r = 0; r < 4; ++r) mx[r] = wmaxr(mx[r]);
    float sm[4] = {0.f, 0.f, 0.f, 0.f};
#pragma unroll
    for (int c = 0; c < 8; ++c)
#pragma unroll
        for (int r = 0; r < 4; ++r) { sc[c][r] = __expf(sc[c][r] - mx[r]); sm[r] += sc[c][r]; }
#pragma unroll
    for (int r = 0; r < 4; ++r) sm[r] = 1.0f / wsum(sm[r]);
#pragma unroll
    for (int c = 0; c < 8; ++c)
#pragma unroll
        for (int r = 0; r < 4; ++r) sc[c][r] *= sm[r];
    __syncthreads();                             // all waves done reading kt (K)
    // stage V tile over kt
    {
        const float4* s = (const float4*)(VTin + ((size_t)(b * 64 + hh * 16)) * 512);
        float4* d = (float4*)kt;
#pragma unroll
        for (int u = 0; u < 8; ++u) d[t + u * 256] = s[t + u * 256];
    }
    __syncthreads();
    // PV: per-lane partials over this lane's 8 j values
    float acc[4][16];
#pragma unroll
    for (int r = 0; r < 4; ++r)
#pragma unroll
        for (int d = 0; d < 16; ++d) acc[r][d] = 0.f;
#pragma unroll
    for (int c = 0; c < 8; ++c) {
        int j = c * 64 + lane;
#pragma unroll
        for (int d = 0; d < 16; ++d) {
            float v = kt[d * 512 + j];
#pragma unroll
            for (int r = 0; r < 4; ++r) acc[r][d] += sc[c][r] * v;
        }
    }
#pragma unroll
    for (int r = 0; r < 4; ++r)
#pragma unroll
        for (int d = 0; d < 16; ++d) {
            acc[r][d] += __shfl_xor(acc[r][d], 16);
            acc[r][d] += __shfl_xor(acc[r][d], 32);
        }
    // wave-private scratch in own bias rows (only this wave read them)
    float* scr = bv + wv * 2048;                 // 16 x stride-65, conflict-free
    if (lane < 16) {
#pragma unroll
        for (int r = 0; r < 4; ++r)
#pragma unroll
            for (int d = 0; d < 16; ++d) scr[lane * 65 + r * 16 + d] = acc[r][d];
    }
    float o = 0.f;
#pragma unroll
    for (int m = 0; m < 16; ++m) o += scr[m * 65 + lane];
    attO[((size_t)(b * 512 + rbase + (lane >> 4))) * 64 + hh * 16 + (lane & 15)] = o;
}

// =================== kLF: oproj + LN1 + FFN + LN2 + qkv(l+1) [+ egoAcc at l=2] ===================
// grid 512 x 256 : wave per row
__global__ __launch_bounds__(256) void kLF(
    const float* __restrict__ attO,
    const float* __restrict__ wow, const float* __restrict__ wob,
    const float* __restrict__ ln1g, const float* __restrict__ ln1b,
    const float* __restrict__ f1w, const float* __restrict__ f1b,
    const float* __restrict__ f2w, const float* __restrict__ f2b,
    const float* __restrict__ ln2g, const float* __restrict__ ln2b,
    const float* __restrict__ wqn, const float* __restrict__ wkn, const float* __restrict__ wvn,
    const float* __restrict__ sc1w, const float* __restrict__ sc1b,
    float* __restrict__ hbuf, float* __restrict__ QbOut,
    float* __restrict__ KTout, float* __restrict__ VTout,
    float* __restrict__ egoAcc, int l, float* __restrict__ out)
{
    int t = threadIdx.x, wv = t >> 6, lane = t & 63;
    int g = blockIdx.x * 4 + wv;
    int b = g >> 9, srow = g & 511;
    float hv = hbuf[(size_t)g * 64 + lane];
    float att = attO[(size_t)g * 64 + lane];
    // oproj + residual + LN1
    float h1;
    {
        float a = wob[l * 64 + lane];
        const float* Wo = wow + l * 4096;
        for (int k = 0; k < 64; ++k) a += __shfl(att, k) * Wo[k * 64 + lane];
        float xx = a + hv;
        float mn = wsum(xx) * 0.015625f;
        float d = xx - mn;
        float var = wsum(d * d) * 0.015625f;
        h1 = d * rsqrtf(var + 1e-5f) * ln1g[l * 64 + lane] + ln1b[l * 64 + lane];
    }
    // FFN + residual + LN2
    float hn;
    {
        const float* W1 = f1w + l * 16384;
        const float* W2 = f2w + l * 16384;
        float a1[4];
#pragma unroll
        for (int m = 0; m < 4; ++m) a1[m] = f1b[l * 256 + m * 64 + lane];
        for (int k = 0; k < 64; ++k) {
            float hk = __shfl(h1, k);
#pragma unroll
            for (int m = 0; m < 4; ++m) a1[m] += hk * W1[k * 256 + m * 64 + lane];
        }
        float ffv[4];
#pragma unroll
        for (int m = 0; m < 4; ++m) {
            float u = a1[m];
            ffv[m] = 0.5f * u * (1.0f + erff(u * 0.70710678118654752f));
        }
        // 4 independent accumulator chains (was 1 x 256-step chain)
        float a2p0 = 0.f, a2p1 = 0.f, a2p2 = 0.f, a2p3 = 0.f;
        for (int ll = 0; ll < 64; ++ll) {
            a2p0 += __shfl(ffv[0], ll) * W2[(ll) * 64 + lane];
            a2p1 += __shfl(ffv[1], ll) * W2[(64 + ll) * 64 + lane];
            a2p2 += __shfl(ffv[2], ll) * W2[(128 + ll) * 64 + lane];
            a2p3 += __shfl(ffv[3], ll) * W2[(192 + ll) * 64 + lane];
        }
        float a2 = ((a2p0 + a2p1) + a2p2) + a2p3;
        float xx = a2 + f2b[l * 64 + lane] + h1;
        float mn = wsum(xx) * 0.015625f;
        float d = xx - mn;
        float var = wsum(d * d) * 0.015625f;
        hn = d * rsqrtf(var + 1e-5f) * ln2g[l * 64 + lane] + ln2b[l * 64 + lane];
    }
    hbuf[(size_t)g * 64 + lane] = hn;
    if (l == 2) {
        out[2044 + (size_t)g * 64 + lane] = hn;
        if (srow == 0) {
            float ea = sc1b[lane];
            for (int k = 0; k < 64; ++k) ea += __shfl(hn, k) * sc1w[k * 64 + lane];
            egoAcc[b * 64 + lane] = ea;
        }
    } else {
        float aq = 0.f, ak = 0.f, av = 0.f;
        for (int k = 0; k < 64; ++k) {
            float hk = __shfl(hn, k);
            aq += hk * wqn[k * 64 + lane];
            ak += hk * wkn[k * 64 + lane];
            av += hk * wvn[k * 64 + lane];
        }
        QbOut[(size_t)g * 64 + lane] = aq;
        KTout[((size_t)(b * 64 + lane)) * 512 + srow] = ak;
        VTout[((size_t)(b * 64 + lane)) * 512 + srow] = av;
    }
}

// =================== kS: scoring head (ego half precomputed) ===================
// grid 511 x 256 : wave per candidate
__global__ __launch_bounds__(256) void kS(
    const float* __restrict__ hbuf, const float* __restrict__ egoAcc,
    const float* __restrict__ s1w,
    const float* __restrict__ lng, const float* __restrict__ lnb,
    const float* __restrict__ s2w, const float* __restrict__ s2b,
    float* __restrict__ logits)
{
    int t = threadIdx.x, wv = t >> 6, lane = t & 63;
    int wid = blockIdx.x * 4 + wv;               // 0..2043
    if (wid >= 2044) return;
    int bb = wid / 511; int jj = wid % 511; int j = jj + 1;
    float cand = hbuf[((size_t)(bb * 512 + j)) * 64 + lane];
    float acc = egoAcc[bb * 64 + lane];
    for (int k = 0; k < 64; ++k) acc += __shfl(cand, k) * s1w[(64 + k) * 64 + lane];
    float mn = wsum(acc) * 0.015625f;
    float d = acc - mn;
    float var = wsum(d * d) * 0.015625f;
    float x = d * rsqrtf(var + 1e-5f) * lng[lane] + lnb[lane];
    x = x >= 0.f ? x : 0.2f * x;
    float p = wsum(x * s2w[lane]);
    if (lane == 0) logits[wid] = p + s2b[0];
}

// =================== kP: final softmax over candidates ===================
// grid 4 x 512
__global__ __launch_bounds__(512) void kP(
    const float* __restrict__ logits, const int* __restrict__ nmask, float* __restrict__ out)
{
    __shared__ float red[512];
    __shared__ int anyf;
    int b = blockIdx.x; int t = threadIdx.x;
    bool cand = false;
    if (t < 511) cand = nmask[b * 512 + 1 + t] != 0;
    if (t == 0) anyf = 0;
    __syncthreads();
    if (cand) atomicOr(&anyf, 1);
    __syncthreads();
    if (t == 0 && anyf == 0) cand = true;
    float val = -3e38f;
    if (t < 511) val = cand ? logits[b * 511 + t] : -1e9f;
    red[t] = val; __syncthreads();
    for (int s = 256; s > 0; s >>= 1) { if (t < s) red[t] = fmaxf(red[t], red[t + s]); __syncthreads(); }
    float m = red[0]; __syncthreads();
    float p = (t < 511) ? __expf(val - m) : 0.f;
    red[t] = p; __syncthreads();
    for (int s = 256; s > 0; s >>= 1) { if (t < s) red[t] += red[t + s]; __syncthreads(); }
    float inv = 1.0f / red[0];
    if (t < 511) out[b * 511 + t] = p * inv;
}

extern "C" void kernel_launch(void* const* d_in, const int* in_sizes, int n_in,
                              void* d_out, int out_size, void* d_ws, size_t ws_size,
                              hipStream_t stream) {
    const float* nf    = (const float*)d_in[0];
    const float* ef    = (const float*)d_in[1];
    const int*   nm    = (const int*)d_in[2];
    const int*   em    = (const int*)d_in[3];
    const float* npw   = (const float*)d_in[4];
    const float* npb   = (const float*)d_in[5];
    const float* epw   = (const float*)d_in[6];
    const float* epb   = (const float*)d_in[7];
    const float* wq    = (const float*)d_in[8];
    const float* wk    = (const float*)d_in[9];
    const float* wv    = (const float*)d_in[10];
    const float* eb1w  = (const float*)d_in[11];
    const float* eb1b  = (const float*)d_in[12];
    const float* eblng = (const float*)d_in[13];
    const float* eblnb = (const float*)d_in[14];
    const float* eb2w  = (const float*)d_in[15];
    const float* eb2b  = (const float*)d_in[16];
    const float* s1wv  = (const float*)d_in[17];
    const float* s1bv  = (const float*)d_in[18];
    const float* s2wv  = (const float*)d_in[19];
    const float* s2bv  = (const float*)d_in[20];
    const float* wow   = (const float*)d_in[21];
    const float* wob   = (const float*)d_in[22];
    const float* ln1g  = (const float*)d_in[23];
    const float* ln1b  = (const float*)d_in[24];
    const float* ln2g  = (const float*)d_in[25];
    const float* ln2b  = (const float*)d_in[26];
    const float* f1w   = (const float*)d_in[27];
    const float* f1b   = (const float*)d_in[28];
    const float* f2w   = (const float*)d_in[29];
    const float* f2b   = (const float*)d_in[30];
    const float* sc1w  = (const float*)d_in[31];
    const float* sc1b  = (const float*)d_in[32];
    const float* sclng = (const float*)d_in[33];
    const float* sclnb = (const float*)d_in[34];
    const float* sc2w  = (const float*)d_in[35];
    const float* sc2b  = (const float*)d_in[36];

    char* W = (char*)d_ws;
    u64*   adj    = (u64*)(W + 0);              //   131,072 B
    unsigned char* spd = (unsigned char*)(W + 131072);   // 1,048,576 B
    u32*   elist  = (u32*)(W + 1179648);        //   786,432 B [2048][96]
    u32*   rowCnt = (u32*)(W + 1966080);        //     8,192 B
    float* vals   = (float*)(W + 1974272);      // 9,437,184 B [12][2048*96]
    float* hbuf   = (float*)(W + 11411456);     //   524,288 B
    float* Qb     = (float*)(W + 11935744);     //   524,288 B
    float* KT0    = (float*)(W + 12460032);     //   524,288 B
    float* VT0    = (float*)(W + 12984320);     //   524,288 B
    float* KT1    = (float*)(W + 13508608);     //   524,288 B
    float* VT1    = (float*)(W + 14032896);     //   524,288 B
    float* logits = (float*)(W + 14557184);     //     8,192 B
    float* egoAcc = (float*)(W + 14565376);     //     1,024 B
    float* attO   = (float*)(W + 14566400);     //   524,288 B

    float* out = (float*)d_out;                 // [probs 2044][h 131072]

    kA<<<512, 256, 0, stream>>>(em, nf, npw, npb, adj, elist, rowCnt, hbuf);
    kB<<<512, 256, 0, stream>>>(adj, ef, elist, rowCnt, hbuf, epw, epb,
                                eb1w, eb1b, eblng, eblnb, eb2w, eb2b,
                                wq, wk, wv, spd, vals, Qb, KT0, VT0);

    kAttn<<<512, 256, 0, stream>>>(Qb, KT0, VT0, spd, elist, rowCnt, vals,
                                   s1wv, s1bv, s2wv, s2bv, nm, 0, attO);
    kLF<<<512, 256, 0, stream>>>(attO, wow, wob, ln1g, ln1b, f1w, f1b, f2w, f2b,
                                 ln2g, ln2b, wq + 4096, wk + 4096, wv + 4096,
                                 sc1w, sc1b, hbuf, Qb, KT1, VT1, egoAcc, 0, out);

    kAttn<<<512, 256, 0, stream>>>(Qb, KT1, VT1, spd, elist, rowCnt, vals,
                                   s1wv, s1bv, s2wv, s2bv, nm, 1, attO);
    kLF<<<512, 256, 0, stream>>>(attO, wow, wob, ln1g, ln1b, f1w, f1b, f2w, f2b,
                                 ln2g, ln2b, wq + 8192, wk + 8192, wv + 8192,
                                 sc1w, sc1b, hbuf, Qb, KT0, VT0, egoAcc, 1, out);

    kAttn<<<512, 256, 0, stream>>>(Qb, KT0, VT0, spd, elist, rowCnt, vals,
                                   s1wv, s1bv, s2wv, s2bv, nm, 2, attO);
    kLF<<<512, 256, 0, stream>>>(attO, wow, wob, ln1g, ln1b, f1w, f1b, f2w, f2b,
                                 ln2g, ln2b, wq, wk, wv,
                                 sc1w, sc1b, hbuf, Qb, KT1, VT1, egoAcc, 2, out);

    kS<<<511, 256, 0, stream>>>(hbuf, egoAcc, sc1w, sclng, sclnb, sc2w, sc2b, logits);
    kP<<<4, 512, 0, stream>>>(logits, nm, out);
}